// Round 6
// baseline (83.827 us; speedup 1.0000x reference)
//
#include <hip/hip_runtime.h>
#include <math.h>

namespace {
constexpr int P = 4096, O = 32, H = 26, V = 48;
constexpr int PPB = 128;              // points per block (2 lanes per point)
constexpr float EPSV = 1e-4f;         // strict < EPSV == numpy's (f32 <= 1e-4 f64)
}

// 2 lanes per (point p, object o): lane 0 owns faces h in [0,13) and edges
// v in [0,24); lane 1 owns h in [13,26), v in [24,48). Each face's full 26-j
// projection test stays with its owner lane -> per-face arithmetic is
// bit-identical to the serial kernel (numpy rounding: separate mul/add, no
// FMA, sequential 3-term sums, IEEE div/sqrt). A single shfl_xor(1) symmetric
// merge with contiguous-range tiebreaks reproduces numpy first-index
// argmax/argmin exactly.
__global__ __launch_bounds__(256, 4) void zono_kernel(
    const float* __restrict__ point,   // [P][3]
    const float* __restrict__ hA,      // [O][H][3]
    const float* __restrict__ hb,      // [O][H]
    const float* __restrict__ v1g,     // [O][V][3]
    const float* __restrict__ v2g,     // [O][V][3]
    float* __restrict__ dist_out,      // [P][O]
    float* __restrict__ grad_out)      // [P][O][3]
{
    __shared__ float4 sAb[H];   // {a0,a1,a2,b}
    __shared__ float4 sV1[V];   // {v1_0,v1_1,v1_2,denom}
    __shared__ float4 sE[V];    // {e0,e1,e2,unused}

    const int o   = blockIdx.y;
    const int tid = threadIdx.x;

    if (tid < H) {
        const float* a = hA + (o * H + tid) * 3;
        sAb[tid] = make_float4(a[0], a[1], a[2], hb[o * H + tid]);
    } else if (tid >= 32 && tid < 32 + V) {
        const int v = tid - 32;
        const float* A1 = v1g + (o * V + v) * 3;
        const float* A2 = v2g + (o * V + v) * 3;
        const float x0 = A1[0], x1 = A1[1], x2 = A1[2];
        const float e0 = __fsub_rn(A2[0], x0);
        const float e1 = __fsub_rn(A2[1], x1);
        const float e2 = __fsub_rn(A2[2], x2);
        const float den = __fadd_rn(__fadd_rn(__fmul_rn(e0, e0), __fmul_rn(e1, e1)),
                                    __fmul_rn(e2, e2));
        sV1[v] = make_float4(x0, x1, x2, den);
        sE[v]  = make_float4(e0, e1, e2, 0.f);
    }
    __syncthreads();

    const int lane = tid & 1;                       // 0: low half, 1: high half
    const int p    = blockIdx.x * PPB + (tid >> 1);
    const float p0 = point[p * 3 + 0];
    const float p1 = point[p * 3 + 1];
    const float p2 = point[p * 3 + 2];

    // ---- face pass over this lane's faces (full j-test per face) ----
    const int h0 = lane ? 13 : 0;
    const int h1 = lane ? H  : 13;

    bool  is_neg  = true;
    float maxv    = -INFINITY; int maxi = h0;
    float minperp =  INFINITY; int mini = h0;

    for (int h = h0; h < h1; ++h) {
        const float4 ab = sAb[h];                   // 2 addrs/wave: free
        const float sh = __fsub_rn(
            __fadd_rn(__fadd_rn(__fmul_rn(p0, ab.x), __fmul_rn(p1, ab.y)),
                      __fmul_rn(p2, ab.z)),
            ab.w);
        if (sh > 0.f) is_neg = false;
        if (sh > maxv) { maxv = sh; maxi = h; }     // first argmax in-range

        const float pp0 = __fsub_rn(p0, __fmul_rn(sh, ab.x));
        const float pp1 = __fsub_rn(p1, __fmul_rn(sh, ab.y));
        const float pp2 = __fsub_rn(p2, __fmul_rn(sh, ab.z));

        // onz = all_j (t_j < EPSV) == max_j t_j < EPSV  (broadcast LDS reads)
        float m0 = -INFINITY, m1 = -INFINITY;
        #pragma unroll
        for (int j = 0; j < H; j += 2) {            // H=26: 13 pairs
            const float4 qa = sAb[j];
            const float ta = __fsub_rn(
                __fadd_rn(__fadd_rn(__fmul_rn(pp0, qa.x), __fmul_rn(pp1, qa.y)),
                          __fmul_rn(pp2, qa.z)),
                qa.w);
            m0 = fmaxf(m0, ta);
            const float4 qb = sAb[j + 1];
            const float tb = __fsub_rn(
                __fadd_rn(__fadd_rn(__fmul_rn(pp0, qb.x), __fmul_rn(pp1, qb.y)),
                          __fmul_rn(pp2, qb.z)),
                qb.w);
            m1 = fmaxf(m1, tb);
        }
        const bool onz = (fmaxf(m0, m1) < EPSV);

        const float d0 = __fsub_rn(p0, pp0);
        const float d1 = __fsub_rn(p1, pp1);
        const float d2 = __fsub_rn(p2, pp2);
        float perp = __fsqrt_rn(
            __fadd_rn(__fadd_rn(__fmul_rn(d0, d0), __fmul_rn(d1, d1)),
                      __fmul_rn(d2, d2)));
        if (!onz) perp = INFINITY;
        if (perp < minperp) { minperp = perp; mini = h; }  // first argmin in-range
    }

    // ---- edge pass over this lane's edges ----
    const int v0 = lane ? 24 : 0;
    const int v1 = lane ? V  : 24;

    float mine = INFINITY; int midx = v0;
    float vm0 = 0.f, vm1 = 0.f, vm2 = 0.f;
    #pragma unroll 2
    for (int v = v0; v < v1; ++v) {
        const float4 V1 = sV1[v];
        const float4 E  = sE[v];
        const float w0 = __fsub_rn(p0, V1.x);
        const float w1 = __fsub_rn(p1, V1.y);
        const float w2 = __fsub_rn(p2, V1.z);
        const float th = __fdiv_rn(
            __fadd_rn(__fadd_rn(__fmul_rn(w0, E.x), __fmul_rn(w1, E.y)),
                      __fmul_rn(w2, E.z)),
            V1.w);
        const float ts = fminf(fmaxf(th, 0.f), 1.f);
        const float q0 = __fadd_rn(V1.x, __fmul_rn(ts, E.x));
        const float q1 = __fadd_rn(V1.y, __fmul_rn(ts, E.y));
        const float q2 = __fadd_rn(V1.z, __fmul_rn(ts, E.z));
        const float g0 = __fsub_rn(p0, q0);
        const float g1 = __fsub_rn(p1, q1);
        const float g2 = __fsub_rn(p2, q2);
        const float ed = __fsqrt_rn(
            __fadd_rn(__fadd_rn(__fmul_rn(g0, g0), __fmul_rn(g1, g1)),
                      __fmul_rn(g2, g2)));
        if (ed < mine) { mine = ed; midx = v; vm0 = q0; vm1 = q1; vm2 = q2; }
    }

    // ---- symmetric pair merge (both lanes end with identical state) ----
    {
        unsigned negu = is_neg ? 1u : 0u;
        negu &= (unsigned)__shfl_xor((int)negu, 1);
        is_neg = (negu != 0u);

        const float ovx = __shfl_xor(maxv, 1);
        const int   oix = __shfl_xor(maxi, 1);
        bool take = (ovx > maxv) || (ovx == maxv && oix < maxi);
        maxv = take ? ovx : maxv;  maxi = take ? oix : maxi;

        const float ovm = __shfl_xor(minperp, 1);
        const int   oim = __shfl_xor(mini, 1);
        take = (ovm < minperp) || (ovm == minperp && oim < mini);
        minperp = take ? ovm : minperp;  mini = take ? oim : mini;

        const float ove  = __shfl_xor(mine, 1);
        const int   oie  = __shfl_xor(midx, 1);
        const float ov0  = __shfl_xor(vm0, 1);
        const float ov1  = __shfl_xor(vm1, 1);
        const float ov2  = __shfl_xor(vm2, 1);
        take = (ove < mine) || (ove == mine && oie < midx);
        mine = take ? ove : mine;  midx = take ? oie : midx;
        vm0 = take ? ov0 : vm0;  vm1 = take ? ov1 : vm1;  vm2 = take ? ov2 : vm2;
    }

    // ---- select (identical on both lanes; even lane stores) ----
    const int   fidx = is_neg ? maxi : mini;
    const float4 ga  = sAb[fidx];
    float dist = is_neg ? maxv : minperp;
    float g0 = ga.x, g1 = ga.y, g2 = ga.z;
    if (!is_neg && (mine < dist)) {
        dist = mine;
        g0 = __fdiv_rn(__fsub_rn(p0, vm0), mine);
        g1 = __fdiv_rn(__fsub_rn(p1, vm1), mine);
        g2 = __fdiv_rn(__fsub_rn(p2, vm2), mine);
    }

    if (lane == 0) {
        const int idx = p * O + o;
        dist_out[idx] = dist;
        grad_out[idx * 3 + 0] = g0;
        grad_out[idx * 3 + 1] = g1;
        grad_out[idx * 3 + 2] = g2;
    }
}

extern "C" void kernel_launch(void* const* d_in, const int* in_sizes, int n_in,
                              void* d_out, int out_size, void* d_ws, size_t ws_size,
                              hipStream_t stream) {
    const float* point = (const float*)d_in[0];
    const float* hA    = (const float*)d_in[1];
    const float* hb    = (const float*)d_in[2];
    const float* v1    = (const float*)d_in[3];
    const float* v2    = (const float*)d_in[4];
    float* out = (float*)d_out;

    dim3 grid(P / PPB, O);
    zono_kernel<<<grid, dim3(256), 0, stream>>>(point, hA, hb, v1, v2,
                                                out, out + P * O);
}

// Round 7
// 28.253 us; speedup vs baseline: 2.9670x; 2.9670x over previous
//
#include <hip/hip_runtime.h>
#include <math.h>

namespace {
constexpr int P = 4096, O = 32, H = 26, V = 48;
constexpr int PPB = 128;              // points per block (2 lanes per point)
constexpr float EPSV = 1e-4f;         // strict < EPSV == numpy's (f32 <= 1e-4 f64)
}

// 2 lanes per (point p, object o): lane 0 owns faces h in [0,13) and edges
// v in [0,24); lane 1 owns h in [13,26), v in [24,48). Each face's full 26-j
// projection test stays with its owner lane -> per-face arithmetic is
// bit-identical to the serial kernel (numpy rounding: separate mul/add, no
// FMA, sequential 3-term sums, IEEE div/sqrt). A single shfl_xor(1) symmetric
// merge with contiguous-range tiebreaks reproduces numpy first-index
// argmax/argmin exactly.
//
// NOTE: no min-waves arg in __launch_bounds__ — (256,4) caps VGPR at 64 and
// spills ~32 regs (R4/R6: FETCH 70-170MB of scratch traffic, 3x slowdown).
// At natural ~100 VGPR the HW gives 16 waves/CU = 4/SIMD, which is what the
// 1024-block grid provides.
__global__ __launch_bounds__(256) void zono_kernel(
    const float* __restrict__ point,   // [P][3]
    const float* __restrict__ hA,      // [O][H][3]
    const float* __restrict__ hb,      // [O][H]
    const float* __restrict__ v1g,     // [O][V][3]
    const float* __restrict__ v2g,     // [O][V][3]
    float* __restrict__ dist_out,      // [P][O]
    float* __restrict__ grad_out)      // [P][O][3]
{
    __shared__ float4 sAb[H];   // {a0,a1,a2,b}
    __shared__ float4 sV1[V];   // {v1_0,v1_1,v1_2,denom}
    __shared__ float4 sE[V];    // {e0,e1,e2,unused}

    const int o   = blockIdx.y;
    const int tid = threadIdx.x;

    if (tid < H) {
        const float* a = hA + (o * H + tid) * 3;
        sAb[tid] = make_float4(a[0], a[1], a[2], hb[o * H + tid]);
    } else if (tid >= 32 && tid < 32 + V) {
        const int v = tid - 32;
        const float* A1 = v1g + (o * V + v) * 3;
        const float* A2 = v2g + (o * V + v) * 3;
        const float x0 = A1[0], x1 = A1[1], x2 = A1[2];
        const float e0 = __fsub_rn(A2[0], x0);
        const float e1 = __fsub_rn(A2[1], x1);
        const float e2 = __fsub_rn(A2[2], x2);
        const float den = __fadd_rn(__fadd_rn(__fmul_rn(e0, e0), __fmul_rn(e1, e1)),
                                    __fmul_rn(e2, e2));
        sV1[v] = make_float4(x0, x1, x2, den);
        sE[v]  = make_float4(e0, e1, e2, 0.f);
    }
    __syncthreads();

    const int lane = tid & 1;                       // 0: low half, 1: high half
    const int p    = blockIdx.x * PPB + (tid >> 1);
    const float p0 = point[p * 3 + 0];
    const float p1 = point[p * 3 + 1];
    const float p2 = point[p * 3 + 2];

    // ---- face pass over this lane's faces (full j-test per face) ----
    const int h0 = lane ? 13 : 0;
    const int h1 = lane ? H  : 13;

    bool  is_neg  = true;
    float maxv    = -INFINITY; int maxi = h0;
    float minperp =  INFINITY; int mini = h0;

    for (int h = h0; h < h1; ++h) {
        const float4 ab = sAb[h];                   // 2 addrs/wave: free
        const float sh = __fsub_rn(
            __fadd_rn(__fadd_rn(__fmul_rn(p0, ab.x), __fmul_rn(p1, ab.y)),
                      __fmul_rn(p2, ab.z)),
            ab.w);
        if (sh > 0.f) is_neg = false;
        if (sh > maxv) { maxv = sh; maxi = h; }     // first argmax in-range

        const float pp0 = __fsub_rn(p0, __fmul_rn(sh, ab.x));
        const float pp1 = __fsub_rn(p1, __fmul_rn(sh, ab.y));
        const float pp2 = __fsub_rn(p2, __fmul_rn(sh, ab.z));

        // onz = all_j (t_j < EPSV) == max_j t_j < EPSV  (broadcast LDS reads)
        float m0 = -INFINITY, m1 = -INFINITY;
        #pragma unroll
        for (int j = 0; j < H; j += 2) {            // H=26: 13 pairs
            const float4 qa = sAb[j];
            const float ta = __fsub_rn(
                __fadd_rn(__fadd_rn(__fmul_rn(pp0, qa.x), __fmul_rn(pp1, qa.y)),
                          __fmul_rn(pp2, qa.z)),
                qa.w);
            m0 = fmaxf(m0, ta);
            const float4 qb = sAb[j + 1];
            const float tb = __fsub_rn(
                __fadd_rn(__fadd_rn(__fmul_rn(pp0, qb.x), __fmul_rn(pp1, qb.y)),
                          __fmul_rn(pp2, qb.z)),
                qb.w);
            m1 = fmaxf(m1, tb);
        }
        const bool onz = (fmaxf(m0, m1) < EPSV);

        const float d0 = __fsub_rn(p0, pp0);
        const float d1 = __fsub_rn(p1, pp1);
        const float d2 = __fsub_rn(p2, pp2);
        float perp = __fsqrt_rn(
            __fadd_rn(__fadd_rn(__fmul_rn(d0, d0), __fmul_rn(d1, d1)),
                      __fmul_rn(d2, d2)));
        if (!onz) perp = INFINITY;
        if (perp < minperp) { minperp = perp; mini = h; }  // first argmin in-range
    }

    // ---- edge pass over this lane's edges ----
    const int v0 = lane ? 24 : 0;
    const int v1 = lane ? V  : 24;

    float mine = INFINITY; int midx = v0;
    float vm0 = 0.f, vm1 = 0.f, vm2 = 0.f;
    #pragma unroll 2
    for (int v = v0; v < v1; ++v) {
        const float4 V1 = sV1[v];
        const float4 E  = sE[v];
        const float w0 = __fsub_rn(p0, V1.x);
        const float w1 = __fsub_rn(p1, V1.y);
        const float w2 = __fsub_rn(p2, V1.z);
        const float th = __fdiv_rn(
            __fadd_rn(__fadd_rn(__fmul_rn(w0, E.x), __fmul_rn(w1, E.y)),
                      __fmul_rn(w2, E.z)),
            V1.w);
        const float ts = fminf(fmaxf(th, 0.f), 1.f);
        const float q0 = __fadd_rn(V1.x, __fmul_rn(ts, E.x));
        const float q1 = __fadd_rn(V1.y, __fmul_rn(ts, E.y));
        const float q2 = __fadd_rn(V1.z, __fmul_rn(ts, E.z));
        const float g0 = __fsub_rn(p0, q0);
        const float g1 = __fsub_rn(p1, q1);
        const float g2 = __fsub_rn(p2, q2);
        const float ed = __fsqrt_rn(
            __fadd_rn(__fadd_rn(__fmul_rn(g0, g0), __fmul_rn(g1, g1)),
                      __fmul_rn(g2, g2)));
        if (ed < mine) { mine = ed; midx = v; vm0 = q0; vm1 = q1; vm2 = q2; }
    }

    // ---- symmetric pair merge (both lanes end with identical state) ----
    {
        unsigned negu = is_neg ? 1u : 0u;
        negu &= (unsigned)__shfl_xor((int)negu, 1);
        is_neg = (negu != 0u);

        const float ovx = __shfl_xor(maxv, 1);
        const int   oix = __shfl_xor(maxi, 1);
        bool take = (ovx > maxv) || (ovx == maxv && oix < maxi);
        maxv = take ? ovx : maxv;  maxi = take ? oix : maxi;

        const float ovm = __shfl_xor(minperp, 1);
        const int   oim = __shfl_xor(mini, 1);
        take = (ovm < minperp) || (ovm == minperp && oim < mini);
        minperp = take ? ovm : minperp;  mini = take ? oim : mini;

        const float ove  = __shfl_xor(mine, 1);
        const int   oie  = __shfl_xor(midx, 1);
        const float ov0  = __shfl_xor(vm0, 1);
        const float ov1  = __shfl_xor(vm1, 1);
        const float ov2  = __shfl_xor(vm2, 1);
        take = (ove < mine) || (ove == mine && oie < midx);
        mine = take ? ove : mine;  midx = take ? oie : midx;
        vm0 = take ? ov0 : vm0;  vm1 = take ? ov1 : vm1;  vm2 = take ? ov2 : vm2;
    }

    // ---- select (identical on both lanes; even lane stores) ----
    const int   fidx = is_neg ? maxi : mini;
    const float4 ga  = sAb[fidx];
    float dist = is_neg ? maxv : minperp;
    float g0 = ga.x, g1 = ga.y, g2 = ga.z;
    if (!is_neg && (mine < dist)) {
        dist = mine;
        g0 = __fdiv_rn(__fsub_rn(p0, vm0), mine);
        g1 = __fdiv_rn(__fsub_rn(p1, vm1), mine);
        g2 = __fdiv_rn(__fsub_rn(p2, vm2), mine);
    }

    if (lane == 0) {
        const int idx = p * O + o;
        dist_out[idx] = dist;
        grad_out[idx * 3 + 0] = g0;
        grad_out[idx * 3 + 1] = g1;
        grad_out[idx * 3 + 2] = g2;
    }
}

extern "C" void kernel_launch(void* const* d_in, const int* in_sizes, int n_in,
                              void* d_out, int out_size, void* d_ws, size_t ws_size,
                              hipStream_t stream) {
    const float* point = (const float*)d_in[0];
    const float* hA    = (const float*)d_in[1];
    const float* hb    = (const float*)d_in[2];
    const float* v1    = (const float*)d_in[3];
    const float* v2    = (const float*)d_in[4];
    float* out = (float*)d_out;

    dim3 grid(P / PPB, O);
    zono_kernel<<<grid, dim3(256), 0, stream>>>(point, hA, hb, v1, v2,
                                                out, out + P * O);
}

// Round 8
// 24.440 us; speedup vs baseline: 3.4299x; 1.1560x over previous
//
#include <hip/hip_runtime.h>
#include <math.h>

namespace {
constexpr int P = 4096, O = 32, H = 26, V = 48;
constexpr int GPITCH = 28;            // Gram row stride (floats); 112B rows, 16B-aligned
constexpr float EPSV = 1e-4f;         // strict < EPSV == numpy's (f32 <= 1e-4 f64)
}

// One thread per (point p, object o).
// Gram trick: Appb[h][j] = s_j - s_h * G[h][j], G[h][j] = a_h . a_j  (per-block LDS).
// s_j is computed with rounding bit-identical to the reference's Ap_minus_b, so
// is_neg / argmax / max_vals are exact. pp/perp and the edge pass keep the
// reference's exact op order (separate mul/add, sequential 3-term sums, IEEE
// div/sqrt). Only the on_zono t-values change rounding (~1 ulp) — tolerated by
// the bf16-quantized comparison unless a t sits within ~1e-7 of EPS.
__global__ __launch_bounds__(256) void zono_kernel(
    const float* __restrict__ point,   // [P][3]
    const float* __restrict__ hA,      // [O][H][3]
    const float* __restrict__ hb,      // [O][H]
    const float* __restrict__ v1g,     // [O][V][3]
    const float* __restrict__ v2g,     // [O][V][3]
    float* __restrict__ dist_out,      // [P][O]
    float* __restrict__ grad_out)      // [P][O][3]
{
    __shared__ float4 sAb[H];            // {a0,a1,a2,b}
    __shared__ float  sG[H][GPITCH];     // Gram a_h . a_j
    __shared__ float4 sV1[V];            // {v1_0,v1_1,v1_2,denom}
    __shared__ float4 sE[V];             // {e0,e1,e2,unused}

    const int o   = blockIdx.y;
    const int tid = threadIdx.x;

    if (tid < H) {
        const float* a = hA + (o * H + tid) * 3;
        sAb[tid] = make_float4(a[0], a[1], a[2], hb[o * H + tid]);
    } else if (tid >= 32 && tid < 32 + V) {
        const int v = tid - 32;
        const float* A1 = v1g + (o * V + v) * 3;
        const float* A2 = v2g + (o * V + v) * 3;
        const float x0 = A1[0], x1 = A1[1], x2 = A1[2];
        const float e0 = __fsub_rn(A2[0], x0);
        const float e1 = __fsub_rn(A2[1], x1);
        const float e2 = __fsub_rn(A2[2], x2);
        const float den = __fadd_rn(__fadd_rn(__fmul_rn(e0, e0), __fmul_rn(e1, e1)),
                                    __fmul_rn(e2, e2));
        sV1[v] = make_float4(x0, x1, x2, den);
        sE[v]  = make_float4(e0, e1, e2, 0.f);
    }
    __syncthreads();

    // Build Gram table (our factorization — rounding unconstrained).
    for (int e = tid; e < H * H; e += 256) {
        const int h = e / H;             // compiler magic-div
        const int j = e - h * H;
        const float4 A = sAb[h];
        const float4 B = sAb[j];
        sG[h][j] = __fadd_rn(__fadd_rn(__fmul_rn(A.x, B.x), __fmul_rn(A.y, B.y)),
                             __fmul_rn(A.z, B.z));
    }
    __syncthreads();

    const int p = blockIdx.x * blockDim.x + tid;
    const float p0 = point[p * 3 + 0];
    const float p1 = point[p * 3 + 1];
    const float p2 = point[p * 3 + 2];

    // ---- s_j (exact reference rounding) + is_neg + argmax, ascending ----
    float s[H];                          // compile-time indexed only (unrolled)
    bool  is_neg = true;
    float maxv   = -INFINITY; int maxi = 0;
    #pragma unroll
    for (int j = 0; j < H; ++j) {
        const float4 ab = sAb[j];
        s[j] = __fsub_rn(
            __fadd_rn(__fadd_rn(__fmul_rn(p0, ab.x), __fmul_rn(p1, ab.y)),
                      __fmul_rn(p2, ab.z)),
            ab.w);
        if (s[j] > 0.f) is_neg = false;
        if (s[j] > maxv) { maxv = s[j]; maxi = j; }    // first argmax
    }

    // ---- face pass: on_zono via Gram, perp exact ----
    float minperp = INFINITY; int mini = 0;
    for (int h = 0; h < H; ++h) {
        const float4 ab = sAb[h];
        const float sh = __fsub_rn(                      // == s[h] bitwise
            __fadd_rn(__fadd_rn(__fmul_rn(p0, ab.x), __fmul_rn(p1, ab.y)),
                      __fmul_rn(p2, ab.z)),
            ab.w);

        // t_j = s_j - sh*G[h][j]; onz = max_j t_j < EPSV  (4 fmax chains)
        float m0 = -INFINITY, m1 = -INFINITY, m2 = -INFINITY, m3 = -INFINITY;
        const float4* gRow = reinterpret_cast<const float4*>(&sG[h][0]);
        #pragma unroll
        for (int q = 0; q < 6; ++q) {                    // j = 0..23
            const float4 g = gRow[q];
            m0 = fmaxf(m0, __fsub_rn(s[4 * q + 0], __fmul_rn(sh, g.x)));
            m1 = fmaxf(m1, __fsub_rn(s[4 * q + 1], __fmul_rn(sh, g.y)));
            m2 = fmaxf(m2, __fsub_rn(s[4 * q + 2], __fmul_rn(sh, g.z)));
            m3 = fmaxf(m3, __fsub_rn(s[4 * q + 3], __fmul_rn(sh, g.w)));
        }
        {
            const float2 g = *reinterpret_cast<const float2*>(&sG[h][24]);
            m0 = fmaxf(m0, __fsub_rn(s[24], __fmul_rn(sh, g.x)));
            m1 = fmaxf(m1, __fsub_rn(s[25], __fmul_rn(sh, g.y)));
        }
        const bool onz = (fmaxf(fmaxf(m0, m1), fmaxf(m2, m3)) < EPSV);

        // pp/d/perp with exact reference rounding
        const float pp0 = __fsub_rn(p0, __fmul_rn(sh, ab.x));
        const float pp1 = __fsub_rn(p1, __fmul_rn(sh, ab.y));
        const float pp2 = __fsub_rn(p2, __fmul_rn(sh, ab.z));
        const float d0 = __fsub_rn(p0, pp0);
        const float d1 = __fsub_rn(p1, pp1);
        const float d2 = __fsub_rn(p2, pp2);
        float perp = __fsqrt_rn(
            __fadd_rn(__fadd_rn(__fmul_rn(d0, d0), __fmul_rn(d1, d1)),
                      __fmul_rn(d2, d2)));
        if (!onz) perp = INFINITY;
        if (perp < minperp) { minperp = perp; mini = h; }  // first argmin
    }

    // ---- edge pass (exact reference rounding) ----
    float mine = INFINITY;
    float vm0 = 0.f, vm1 = 0.f, vm2 = 0.f;
    #pragma unroll 2
    for (int v = 0; v < V; ++v) {
        const float4 V1 = sV1[v];
        const float4 E  = sE[v];
        const float w0 = __fsub_rn(p0, V1.x);
        const float w1 = __fsub_rn(p1, V1.y);
        const float w2 = __fsub_rn(p2, V1.z);
        const float th = __fdiv_rn(
            __fadd_rn(__fadd_rn(__fmul_rn(w0, E.x), __fmul_rn(w1, E.y)),
                      __fmul_rn(w2, E.z)),
            V1.w);
        const float ts = fminf(fmaxf(th, 0.f), 1.f);
        const float q0 = __fadd_rn(V1.x, __fmul_rn(ts, E.x));
        const float q1 = __fadd_rn(V1.y, __fmul_rn(ts, E.y));
        const float q2 = __fadd_rn(V1.z, __fmul_rn(ts, E.z));
        const float g0 = __fsub_rn(p0, q0);
        const float g1 = __fsub_rn(p1, q1);
        const float g2 = __fsub_rn(p2, q2);
        const float ed = __fsqrt_rn(
            __fadd_rn(__fadd_rn(__fmul_rn(g0, g0), __fmul_rn(g1, g1)),
                      __fmul_rn(g2, g2)));
        if (ed < mine) { mine = ed; vm0 = q0; vm1 = q1; vm2 = q2; }
    }

    // ---- select ----
    const int   fidx = is_neg ? maxi : mini;
    const float4 ga  = sAb[fidx];      // dynamic index -> one LDS read
    float dist = is_neg ? maxv : minperp;
    float g0 = ga.x, g1 = ga.y, g2 = ga.z;
    if (!is_neg && (mine < dist)) {
        dist = mine;
        g0 = __fdiv_rn(__fsub_rn(p0, vm0), mine);
        g1 = __fdiv_rn(__fsub_rn(p1, vm1), mine);
        g2 = __fdiv_rn(__fsub_rn(p2, vm2), mine);
    }

    const int idx = p * O + o;
    dist_out[idx] = dist;
    grad_out[idx * 3 + 0] = g0;
    grad_out[idx * 3 + 1] = g1;
    grad_out[idx * 3 + 2] = g2;
}

extern "C" void kernel_launch(void* const* d_in, const int* in_sizes, int n_in,
                              void* d_out, int out_size, void* d_ws, size_t ws_size,
                              hipStream_t stream) {
    const float* point = (const float*)d_in[0];
    const float* hA    = (const float*)d_in[1];
    const float* hb    = (const float*)d_in[2];
    const float* v1    = (const float*)d_in[3];
    const float* v2    = (const float*)d_in[4];
    float* out = (float*)d_out;

    dim3 grid(P / 256, O);
    zono_kernel<<<grid, dim3(256), 0, stream>>>(point, hA, hb, v1, v2,
                                                out, out + P * O);
}

// Round 9
// 20.441 us; speedup vs baseline: 4.1009x; 1.1957x over previous
//
#include <hip/hip_runtime.h>
#include <math.h>

namespace {
constexpr int P = 4096, O = 32, H = 26, V = 48;
constexpr int GPITCH = 28;            // Gram row stride (floats); 112B rows, 16B-aligned
constexpr float EPSV = 1e-4f;         // strict < EPSV == numpy's (f32 <= 1e-4 f64)
}

// One thread per (point p, object o).
// Gram trick: Appb[h][j] = s_j - s_h * G[h][j], G = A A^T in LDS.
// Squared-distance trick: __fsqrt_rn is correctly rounded => monotone =>
// sqrt(min(x)) == min(sqrt(x)) bitwise. We min squared perp/edge distances
// (inner rounding identical to the reference's sqrt argument) and sqrt once
// per pass: every OUTPUT VALUE is bit-identical to the reference; only
// near-tie argmin indices can flip (<=1ulp ties).
// Edge pass: th = (p.e - v1.e) * (1/den) with c_v, inv_den precomputed at
// stage time (~2ulp on th, clamped ends insensitive).
__global__ __launch_bounds__(256) void zono_kernel(
    const float* __restrict__ point,   // [P][3]
    const float* __restrict__ hA,      // [O][H][3]
    const float* __restrict__ hb,      // [O][H]
    const float* __restrict__ v1g,     // [O][V][3]
    const float* __restrict__ v2g,     // [O][V][3]
    float* __restrict__ dist_out,      // [P][O]
    float* __restrict__ grad_out)      // [P][O][3]
{
    __shared__ float4 sAb[H];            // {a0,a1,a2,b}
    __shared__ float  sG[H][GPITCH];     // Gram a_h . a_j
    __shared__ float4 sV1[V];            // {v1_0,v1_1,v1_2, inv_den}
    __shared__ float4 sE[V];             // {e0,e1,e2, c_v = v1.e}

    const int o   = blockIdx.y;
    const int tid = threadIdx.x;

    if (tid < H) {
        const float* a = hA + (o * H + tid) * 3;
        sAb[tid] = make_float4(a[0], a[1], a[2], hb[o * H + tid]);
    } else if (tid >= 32 && tid < 32 + V) {
        const int v = tid - 32;
        const float* A1 = v1g + (o * V + v) * 3;
        const float* A2 = v2g + (o * V + v) * 3;
        const float x0 = A1[0], x1 = A1[1], x2 = A1[2];
        const float e0 = __fsub_rn(A2[0], x0);
        const float e1 = __fsub_rn(A2[1], x1);
        const float e2 = __fsub_rn(A2[2], x2);
        const float den = __fadd_rn(__fadd_rn(__fmul_rn(e0, e0), __fmul_rn(e1, e1)),
                                    __fmul_rn(e2, e2));
        const float inv = __fdiv_rn(1.f, den);
        const float cv  = __fadd_rn(__fadd_rn(__fmul_rn(x0, e0), __fmul_rn(x1, e1)),
                                    __fmul_rn(x2, e2));
        sV1[v] = make_float4(x0, x1, x2, inv);
        sE[v]  = make_float4(e0, e1, e2, cv);
    }
    __syncthreads();

    // Build Gram table (our factorization — rounding unconstrained).
    for (int e = tid; e < H * H; e += 256) {
        const int h = e / H;
        const int j = e - h * H;
        const float4 A = sAb[h];
        const float4 B = sAb[j];
        sG[h][j] = __fadd_rn(__fadd_rn(__fmul_rn(A.x, B.x), __fmul_rn(A.y, B.y)),
                             __fmul_rn(A.z, B.z));
    }
    __syncthreads();

    const int p = blockIdx.x * blockDim.x + tid;
    const float p0 = point[p * 3 + 0];
    const float p1 = point[p * 3 + 1];
    const float p2 = point[p * 3 + 2];

    // ---- s_j (exact reference rounding) + argmax; is_neg == (maxv <= 0) ----
    float s[H];                          // compile-time indexed only (unrolled)
    float maxv = -INFINITY; int maxi = 0;
    #pragma unroll
    for (int j = 0; j < H; ++j) {
        const float4 ab = sAb[j];
        s[j] = __fsub_rn(
            __fadd_rn(__fadd_rn(__fmul_rn(p0, ab.x), __fmul_rn(p1, ab.y)),
                      __fmul_rn(p2, ab.z)),
            ab.w);
        if (s[j] > maxv) { maxv = s[j]; maxi = j; }    // first argmax
    }
    const bool is_neg = (maxv <= 0.f);

    // ---- face pass: on_zono via Gram; min of SQUARED perp ----
    float minpsq = INFINITY; int mini = 0;
    for (int h = 0; h < H; ++h) {
        const float4 ab = sAb[h];
        const float sh = __fsub_rn(                      // == s[h] bitwise
            __fadd_rn(__fadd_rn(__fmul_rn(p0, ab.x), __fmul_rn(p1, ab.y)),
                      __fmul_rn(p2, ab.z)),
            ab.w);

        // t_j = s_j - sh*G[h][j]; onz = max_j t_j < EPSV  (4 fmax chains)
        float m0 = -INFINITY, m1 = -INFINITY, m2 = -INFINITY, m3 = -INFINITY;
        const float4* gRow = reinterpret_cast<const float4*>(&sG[h][0]);
        #pragma unroll
        for (int q = 0; q < 6; ++q) {                    // j = 0..23
            const float4 g = gRow[q];
            m0 = fmaxf(m0, __fsub_rn(s[4 * q + 0], __fmul_rn(sh, g.x)));
            m1 = fmaxf(m1, __fsub_rn(s[4 * q + 1], __fmul_rn(sh, g.y)));
            m2 = fmaxf(m2, __fsub_rn(s[4 * q + 2], __fmul_rn(sh, g.z)));
            m3 = fmaxf(m3, __fsub_rn(s[4 * q + 3], __fmul_rn(sh, g.w)));
        }
        {
            const float2 g = *reinterpret_cast<const float2*>(&sG[h][24]);
            m0 = fmaxf(m0, __fsub_rn(s[24], __fmul_rn(sh, g.x)));
            m1 = fmaxf(m1, __fsub_rn(s[25], __fmul_rn(sh, g.y)));
        }
        const bool onz = (fmaxf(fmaxf(m0, m1), fmaxf(m2, m3)) < EPSV);

        // squared perp with exact reference inner rounding
        const float pp0 = __fsub_rn(p0, __fmul_rn(sh, ab.x));
        const float pp1 = __fsub_rn(p1, __fmul_rn(sh, ab.y));
        const float pp2 = __fsub_rn(p2, __fmul_rn(sh, ab.z));
        const float d0 = __fsub_rn(p0, pp0);
        const float d1 = __fsub_rn(p1, pp1);
        const float d2 = __fsub_rn(p2, pp2);
        float psq = __fadd_rn(__fadd_rn(__fmul_rn(d0, d0), __fmul_rn(d1, d1)),
                              __fmul_rn(d2, d2));
        if (!onz) psq = INFINITY;
        if (psq < minpsq) { minpsq = psq; mini = h; }     // first argmin
    }
    const float minperp = __fsqrt_rn(minpsq);  // == min_h sqrt(psq_h) bitwise

    // ---- edge pass: min of SQUARED segment distance ----
    float minesq = INFINITY;
    float vm0 = 0.f, vm1 = 0.f, vm2 = 0.f;
    #pragma unroll 2
    for (int v = 0; v < V; ++v) {
        const float4 V1 = sV1[v];
        const float4 E  = sE[v];
        const float dpe = __fadd_rn(__fadd_rn(__fmul_rn(p0, E.x), __fmul_rn(p1, E.y)),
                                    __fmul_rn(p2, E.z));
        const float th = __fmul_rn(__fsub_rn(dpe, E.w), V1.w);
        const float ts = __builtin_amdgcn_fmed3f(th, 0.f, 1.f);
        const float q0 = __fadd_rn(V1.x, __fmul_rn(ts, E.x));
        const float q1 = __fadd_rn(V1.y, __fmul_rn(ts, E.y));
        const float q2 = __fadd_rn(V1.z, __fmul_rn(ts, E.z));
        const float g0 = __fsub_rn(p0, q0);
        const float g1 = __fsub_rn(p1, q1);
        const float g2 = __fsub_rn(p2, q2);
        const float esq = __fadd_rn(__fadd_rn(__fmul_rn(g0, g0), __fmul_rn(g1, g1)),
                                    __fmul_rn(g2, g2));
        if (esq < minesq) { minesq = esq; vm0 = q0; vm1 = q1; vm2 = q2; }
    }
    const float mine = __fsqrt_rn(minesq);     // == min_v sqrt(esq_v) bitwise

    // ---- select ----
    const int   fidx = is_neg ? maxi : mini;
    const float4 ga  = sAb[fidx];      // dynamic index -> one LDS read
    float dist = is_neg ? maxv : minperp;
    float g0 = ga.x, g1 = ga.y, g2 = ga.z;
    if (!is_neg && (mine < dist)) {
        dist = mine;
        g0 = __fdiv_rn(__fsub_rn(p0, vm0), mine);
        g1 = __fdiv_rn(__fsub_rn(p1, vm1), mine);
        g2 = __fdiv_rn(__fsub_rn(p2, vm2), mine);
    }

    const int idx = p * O + o;
    dist_out[idx] = dist;
    grad_out[idx * 3 + 0] = g0;
    grad_out[idx * 3 + 1] = g1;
    grad_out[idx * 3 + 2] = g2;
}

extern "C" void kernel_launch(void* const* d_in, const int* in_sizes, int n_in,
                              void* d_out, int out_size, void* d_ws, size_t ws_size,
                              hipStream_t stream) {
    const float* point = (const float*)d_in[0];
    const float* hA    = (const float*)d_in[1];
    const float* hb    = (const float*)d_in[2];
    const float* v1    = (const float*)d_in[3];
    const float* v2    = (const float*)d_in[4];
    float* out = (float*)d_out;

    dim3 grid(P / 256, O);
    zono_kernel<<<grid, dim3(256), 0, stream>>>(point, hA, hb, v1, v2,
                                                out, out + P * O);
}